// Round 2
// baseline (304.880 us; speedup 1.0000x reference)
//
#include <hip/hip_runtime.h>

#define BQ_RADIUS2 0.25f
#define KK 32
#define NB 4
#define NP 8192
#define NS 2048
#define C1 32
#define C2 32
#define C3 64
#define EPSBN 1e-5f
#define RTOT 65536          /* S*K */
#define MTOT (NB*NS*KK)     /* 262144 */
#define NSLOT 32

/* workspace offsets (in 4-byte elements) — total 934144 floats = 3.74 MB.
   Intermediate activations y live INSIDE d_out (channels 0..31 of the
   [B][64][RTOT] output buffer) to keep d_ws usage minimal. */
#define OFF_G     0          /* 655360: packed [B][N][20] = xyz + 16 feat + pad */
#define OFF_IDX   655360     /* 262144 ints */
#define OFF_VALID 917504     /* 8192 ints */
#define OFF_P1    925696     /* 2048 = 32 slots * 2*C1 */
#define OFF_P2    927744     /* 2048 */
#define OFF_P3    929792     /* 4096 = 32 slots * 2*C3 */
#define OFF_PAR1  933888     /* 64 */
#define OFF_PAR2  933952     /* 64 */
#define OFF_PAR3  934016     /* 128 */

/* ---- pack pc+feat into AoS g[B][N][20] for fast gathers; zero stat partials ---- */
__global__ __launch_bounds__(256) void k_pack(const float* __restrict__ pc,
                                              const float* __restrict__ feat,
                                              float* __restrict__ g,
                                              float* __restrict__ partials) {
  const int t = blockIdx.x * 256 + threadIdx.x;        /* 0..32767 */
  if (t < 8192) partials[t] = 0.f;                      /* zeros P1,P2,P3 (contiguous) */
  const int b = t >> 13;
  const int j = t & (NP - 1);
  const float* pcb = pc + b * 3 * NP;
  float* gp = g + (size_t)t * 20;
  gp[0] = pcb[j];
  gp[1] = pcb[NP + j];
  gp[2] = pcb[2 * NP + j];
  const float* fb = feat + b * 16 * NP;
#pragma unroll
  for (int c = 0; c < 16; c++) gp[3 + c] = fb[c * NP + j];
  gp[19] = 0.f;
}

/* ---- ball query: one wave per query, 4 points/lane, early exit at K found ---- */
__global__ __launch_bounds__(256) void k_ballquery(const float* __restrict__ pc,
                                                   const float* __restrict__ newpc,
                                                   int* __restrict__ idx,
                                                   int* __restrict__ valid) {
  __shared__ int buf[4][KK];
  const int tid = threadIdx.x;
  const int w = tid >> 6, lane = tid & 63;
  const int gq = blockIdx.x * 4 + w;                    /* 0..8191 */
  const int b = gq >> 11, s = gq & (NS - 1);
  const float* np0 = newpc + b * 3 * NS;
  const float qx = np0[s], qy = np0[NS + s], qz = np0[2 * NS + s];
  const float* px = pc + b * 3 * NP;
  const float* py = px + NP;
  const float* pz = px + 2 * NP;
  if (lane == 0) buf[w][0] = 0;
  int cnt = 0;
  for (int j0 = 0; j0 < NP; j0 += 256) {
    const int jb = j0 + lane * 4;
    const float4 vx = *(const float4*)(px + jb);
    const float4 vy = *(const float4*)(py + jb);
    const float4 vz = *(const float4*)(pz + jb);
    int mm = 0;
    /* d2 with separate rounding, ((dx*dx + dy*dy) + dz*dz), to bit-match np f32 */
    {
      float dx = __fsub_rn(qx, vx.x), dy = __fsub_rn(qy, vy.x), dz = __fsub_rn(qz, vz.x);
      if (__fadd_rn(__fadd_rn(__fmul_rn(dx, dx), __fmul_rn(dy, dy)), __fmul_rn(dz, dz)) < BQ_RADIUS2) mm |= 1;
    }
    {
      float dx = __fsub_rn(qx, vx.y), dy = __fsub_rn(qy, vy.y), dz = __fsub_rn(qz, vz.y);
      if (__fadd_rn(__fadd_rn(__fmul_rn(dx, dx), __fmul_rn(dy, dy)), __fmul_rn(dz, dz)) < BQ_RADIUS2) mm |= 2;
    }
    {
      float dx = __fsub_rn(qx, vx.z), dy = __fsub_rn(qy, vy.z), dz = __fsub_rn(qz, vz.z);
      if (__fadd_rn(__fadd_rn(__fmul_rn(dx, dx), __fmul_rn(dy, dy)), __fmul_rn(dz, dz)) < BQ_RADIUS2) mm |= 4;
    }
    {
      float dx = __fsub_rn(qx, vx.w), dy = __fsub_rn(qy, vy.w), dz = __fsub_rn(qz, vz.w);
      if (__fadd_rn(__fadd_rn(__fmul_rn(dx, dx), __fmul_rn(dy, dy)), __fmul_rn(dz, dz)) < BQ_RADIUS2) mm |= 8;
    }
    const int c4 = __popc(mm);
    int pre = c4;                                       /* inclusive wave prefix-sum */
#pragma unroll
    for (int off = 1; off < 64; off <<= 1) {
      int v = __shfl_up(pre, off);
      if (lane >= off) pre += v;
    }
    const int total = __shfl(pre, 63);
    if (mm) {
      int base = cnt + pre - c4;
#pragma unroll
      for (int i = 0; i < 4; i++) {
        if ((mm >> i) & 1) {
          if (base < KK) buf[w][base] = jb + i;
          base++;
        }
      }
    }
    cnt += total;
    if (cnt >= KK) break;
  }
  __syncthreads();
  if (lane < KK) {
    const int f = cnt < KK ? cnt : KK;
    const int i0 = buf[w][0];                           /* 0 if cnt==0 */
    idx[gq * KK + lane] = (lane < f) ? buf[w][lane] : i0;
  }
  if (lane == 0) valid[gq] = (cnt > 0);
}

/* ---- gather + conv1 (19->32) + stats1; writes channels 0..31 of out ---- */
__global__ __launch_bounds__(256) void k_conv1(const float* __restrict__ g,
                                               const int* __restrict__ idx,
                                               const float* __restrict__ newpc,
                                               const float* __restrict__ w1,
                                               const float* __restrict__ b1,
                                               float* __restrict__ y,
                                               float* __restrict__ partial) {
  __shared__ float wl[C1 * 20];
  __shared__ float bl[C1];
  __shared__ float red[4][2 * C1];
  const int tid = threadIdx.x;
  for (int i = tid; i < C1 * 20; i += 256) {
    const int o = i / 20, c = i - o * 20;
    wl[i] = (c < 19) ? w1[o * 19 + c] : 0.f;
  }
  if (tid < C1) bl[tid] = b1[tid];
  __syncthreads();
  const int pos = blockIdx.x * 256 + tid;
  const int b = pos >> 16;
  const int r = pos & (RTOT - 1);
  const int s = r >> 5;
  const int j = idx[pos];
  const float4* gp = (const float4*)(g + (size_t)(b * NP + j) * 20);
  const float4 v0 = gp[0], v1 = gp[1], v2 = gp[2], v3 = gp[3], v4 = gp[4];
  const float* np0 = newpc + b * 3 * NS;
  float xr[20];
  xr[0] = v0.x - np0[s]; xr[1] = v0.y - np0[NS + s]; xr[2] = v0.z - np0[2 * NS + s]; xr[3] = v0.w;
  xr[4] = v1.x; xr[5] = v1.y; xr[6] = v1.z; xr[7] = v1.w;
  xr[8] = v2.x; xr[9] = v2.y; xr[10] = v2.z; xr[11] = v2.w;
  xr[12] = v3.x; xr[13] = v3.y; xr[14] = v3.z; xr[15] = v3.w;
  xr[16] = v4.x; xr[17] = v4.y; xr[18] = v4.z; xr[19] = v4.w;   /* pad = 0 */
  float sum[C1], sq[C1];
  float* yb = y + ((size_t)b * C3) * RTOT + r;          /* batch stride = 64 channels */
#pragma unroll
  for (int o = 0; o < C1; o++) {
    float acc = bl[o];
    const float4* wr = (const float4*)&wl[o * 20];
#pragma unroll
    for (int ct = 0; ct < 5; ct++) {
      const float4 wv = wr[ct];
      acc = fmaf(wv.x, xr[4 * ct + 0], acc);
      acc = fmaf(wv.y, xr[4 * ct + 1], acc);
      acc = fmaf(wv.z, xr[4 * ct + 2], acc);
      acc = fmaf(wv.w, xr[4 * ct + 3], acc);
    }
    yb[(size_t)o * RTOT] = acc;
    sum[o] = acc; sq[o] = acc * acc;
  }
  const int lane = tid & 63, wv_ = tid >> 6;
#pragma unroll
  for (int o = 0; o < C1; o++) {
    float a = sum[o], q = sq[o];
#pragma unroll
    for (int m = 32; m >= 1; m >>= 1) { a += __shfl_xor(a, m); q += __shfl_xor(q, m); }
    if (lane == 0) { red[wv_][o] = a; red[wv_][C1 + o] = q; }
  }
  __syncthreads();
  if (tid < 2 * C1) {
    const float v = red[0][tid] + red[1][tid] + red[2][tid] + red[3][tid];
    atomicAdd(&partial[(blockIdx.x & (NSLOT - 1)) * 2 * C1 + tid], v);
  }
}

/* ---- bn1+relu fused load, conv2 (32->32) in-place on channels 0..31, stats2 ---- */
__global__ __launch_bounds__(256) void k_conv2(const float* __restrict__ w2,
                                               const float* __restrict__ b2,
                                               const float* __restrict__ par,
                                               float* y,
                                               float* __restrict__ partial) {
  __shared__ float wl[C2 * C1];
  __shared__ float bl[C2];
  __shared__ float pl[2 * C1];
  __shared__ float red[4][2 * C2];
  const int tid = threadIdx.x;
  for (int i = tid; i < C2 * C1; i += 256) wl[i] = w2[i];
  if (tid < C2) bl[tid] = b2[tid];
  if (tid < 2 * C1) pl[tid] = par[tid];
  __syncthreads();
  const int pos = blockIdx.x * 256 + tid;
  const int b = pos >> 16;
  const int r = pos & (RTOT - 1);
  float* yb = y + ((size_t)b * C3) * RTOT + r;
  float xr[C1];
#pragma unroll
  for (int c = 0; c < C1; c++) {
    const float v = yb[(size_t)c * RTOT];
    xr[c] = fmaxf(fmaf(v, pl[c], pl[C1 + c]), 0.f);
  }
  float sum[C2], sq[C2];
#pragma unroll
  for (int o = 0; o < C2; o++) {
    float acc = bl[o];
    const float4* wr = (const float4*)&wl[o * C1];
#pragma unroll
    for (int ct = 0; ct < C1 / 4; ct++) {
      const float4 wv = wr[ct];
      acc = fmaf(wv.x, xr[4 * ct + 0], acc);
      acc = fmaf(wv.y, xr[4 * ct + 1], acc);
      acc = fmaf(wv.z, xr[4 * ct + 2], acc);
      acc = fmaf(wv.w, xr[4 * ct + 3], acc);
    }
    yb[(size_t)o * RTOT] = acc;
    sum[o] = acc; sq[o] = acc * acc;
  }
  const int lane = tid & 63, wv_ = tid >> 6;
#pragma unroll
  for (int o = 0; o < C2; o++) {
    float a = sum[o], q = sq[o];
#pragma unroll
    for (int m = 32; m >= 1; m >>= 1) { a += __shfl_xor(a, m); q += __shfl_xor(q, m); }
    if (lane == 0) { red[wv_][o] = a; red[wv_][C2 + o] = q; }
  }
  __syncthreads();
  if (tid < 2 * C2) {
    const float v = red[0][tid] + red[1][tid] + red[2][tid] + red[3][tid];
    atomicAdd(&partial[(blockIdx.x & (NSLOT - 1)) * 2 * C2 + tid], v);
  }
}

/* ---- bn2+relu fused load, conv3 (32->64) in-place -> all 64 channels, stats3.
   Reads channels 0..31 of its column into registers (all are dependencies of
   every output), then overwrites channels 0..63 of the same column. ---- */
__global__ __launch_bounds__(256) void k_conv3(const float* __restrict__ w3,
                                               const float* __restrict__ b3,
                                               const float* __restrict__ par,
                                               float* y,
                                               float* __restrict__ partial) {
  __shared__ float wl[C3 * C2];
  __shared__ float bl[C3];
  __shared__ float pl[2 * C2];
  __shared__ float red[4][2 * C3];
  const int tid = threadIdx.x;
  for (int i = tid; i < C3 * C2; i += 256) wl[i] = w3[i];
  if (tid < C3) bl[tid] = b3[tid];
  if (tid < 2 * C2) pl[tid] = par[tid];
  __syncthreads();
  const int pos = blockIdx.x * 256 + tid;
  const int b = pos >> 16;
  const int r = pos & (RTOT - 1);
  float* yb = y + ((size_t)b * C3) * RTOT + r;
  float xr[C2];
#pragma unroll
  for (int c = 0; c < C2; c++) {
    const float v = yb[(size_t)c * RTOT];
    xr[c] = fmaxf(fmaf(v, pl[c], pl[C2 + c]), 0.f);
  }
  float sum[C3], sq[C3];
#pragma unroll
  for (int o = 0; o < C3; o++) {
    float acc = bl[o];
    const float4* wr = (const float4*)&wl[o * C2];
#pragma unroll
    for (int ct = 0; ct < C2 / 4; ct++) {
      const float4 wv = wr[ct];
      acc = fmaf(wv.x, xr[4 * ct + 0], acc);
      acc = fmaf(wv.y, xr[4 * ct + 1], acc);
      acc = fmaf(wv.z, xr[4 * ct + 2], acc);
      acc = fmaf(wv.w, xr[4 * ct + 3], acc);
    }
    yb[(size_t)o * RTOT] = acc;
    sum[o] = acc; sq[o] = acc * acc;
  }
  const int lane = tid & 63, wv_ = tid >> 6;
#pragma unroll
  for (int o = 0; o < C3; o++) {
    float a = sum[o], q = sq[o];
#pragma unroll
    for (int m = 32; m >= 1; m >>= 1) { a += __shfl_xor(a, m); q += __shfl_xor(q, m); }
    if (lane == 0) { red[wv_][o] = a; red[wv_][C3 + o] = q; }
  }
  __syncthreads();
  if (tid < 2 * C3) {
    const float v = red[0][tid] + red[1][tid] + red[2][tid] + red[3][tid];
    atomicAdd(&partial[(blockIdx.x & (NSLOT - 1)) * 2 * C3 + tid], v);
  }
}

/* ---- finalize BN params for one layer: partial sums -> (scale, shift) ---- */
__global__ void k_params(const float* __restrict__ partial,
                         const float* __restrict__ gamma,
                         const float* __restrict__ beta,
                         float* __restrict__ params, int C) {
  __shared__ float tot[2 * C3];
  const int t = threadIdx.x;                 /* blockDim == 2C */
  float v = 0.f;
#pragma unroll 1
  for (int sl = 0; sl < NSLOT; ++sl) v += partial[sl * 2 * C + t];
  tot[t] = v;
  __syncthreads();
  if (t < C) {
    const float inv = 1.0f / (float)MTOT;
    const float mean = tot[t] * inv;
    const float ex2 = tot[C + t] * inv;
    const float var = ex2 - mean * mean;
    const float sc = gamma[t] * rsqrtf(var + EPSBN);
    params[t] = sc;
    params[C + t] = beta[t] - mean * sc;
  }
}

/* ---- bn3 + relu + validity mask, in-place on d_out ---- */
__global__ __launch_bounds__(256) void k_final(float* __restrict__ out,
                                               const float* __restrict__ par,
                                               const int* __restrict__ valid) {
  const int t = blockIdx.x * 256 + threadIdx.x;   /* 0..4194303 (float4 per thread) */
  const size_t e = (size_t)t * 4;
  const int b = t >> 20;
  const int o = (t >> 14) & 63;
  const int s = (t & 16383) >> 3;
  const float sc = par[o], sh = par[C3 + o];
  const float m = valid[(b << 11) + s] ? 1.f : 0.f;
  float4 v = *(float4*)(out + e);
  v.x = fmaxf(fmaf(v.x, sc, sh), 0.f) * m;
  v.y = fmaxf(fmaf(v.y, sc, sh), 0.f) * m;
  v.z = fmaxf(fmaf(v.z, sc, sh), 0.f) * m;
  v.w = fmaxf(fmaf(v.w, sc, sh), 0.f) * m;
  *(float4*)(out + e) = v;
}

extern "C" void kernel_launch(void* const* d_in, const int* in_sizes, int n_in,
                              void* d_out, int out_size, void* d_ws, size_t ws_size,
                              hipStream_t stream) {
  const float* pc    = (const float*)d_in[0];
  const float* feat  = (const float*)d_in[1];
  const float* newpc = (const float*)d_in[2];
  const float* w1 = (const float*)d_in[3];
  const float* b1 = (const float*)d_in[4];
  const float* g1 = (const float*)d_in[5];
  const float* be1 = (const float*)d_in[6];
  const float* w2 = (const float*)d_in[7];
  const float* b2 = (const float*)d_in[8];
  const float* g2 = (const float*)d_in[9];
  const float* be2 = (const float*)d_in[10];
  const float* w3 = (const float*)d_in[11];
  const float* b3 = (const float*)d_in[12];
  const float* g3 = (const float*)d_in[13];
  const float* be3 = (const float*)d_in[14];

  float* ws = (float*)d_ws;
  float* gbuf  = ws + OFF_G;
  int*   idx   = (int*)(ws + OFF_IDX);
  int*   valid = (int*)(ws + OFF_VALID);
  float* p1 = ws + OFF_P1;
  float* p2 = ws + OFF_P2;
  float* p3 = ws + OFF_P3;
  float* par1 = ws + OFF_PAR1;
  float* par2 = ws + OFF_PAR2;
  float* par3 = ws + OFF_PAR3;
  float* out = (float*)d_out;

  k_pack<<<dim3(128), dim3(256), 0, stream>>>(pc, feat, gbuf, p1);
  k_ballquery<<<dim3(2048), dim3(256), 0, stream>>>(pc, newpc, idx, valid);
  k_conv1<<<dim3(1024), dim3(256), 0, stream>>>(gbuf, idx, newpc, w1, b1, out, p1);
  k_params<<<dim3(1), dim3(2 * C1), 0, stream>>>(p1, g1, be1, par1, C1);
  k_conv2<<<dim3(1024), dim3(256), 0, stream>>>(w2, b2, par1, out, p2);
  k_params<<<dim3(1), dim3(2 * C2), 0, stream>>>(p2, g2, be2, par2, C2);
  k_conv3<<<dim3(1024), dim3(256), 0, stream>>>(w3, b3, par2, out, p3);
  k_params<<<dim3(1), dim3(2 * C3), 0, stream>>>(p3, g3, be3, par3, C3);
  k_final<<<dim3(16384), dim3(256), 0, stream>>>(out, par3, valid);
}

// Round 3
// 277.491 us; speedup vs baseline: 1.0987x; 1.0987x over previous
//
#include <hip/hip_runtime.h>

#define BQ_RADIUS2 0.25f
#define KK 32
#define NB 4
#define NP 8192
#define NS 2048
#define C1 32
#define C2 32
#define C3 64
#define EPSBN 1e-5f
#define RTOT 65536          /* S*K */
#define MTOT (NB*NS*KK)     /* 262144 */
#define NSLOT 32

/* workspace offsets (in 4-byte elements) — total 934144 floats = 3.74 MB.
   Intermediate activations y live INSIDE d_out (channels 0..31 of the
   [B][64][RTOT] output buffer) to keep d_ws usage minimal. */
#define OFF_G     0          /* 655360: packed [B][N][20] = xyz + 16 feat + pad */
#define OFF_IDX   655360     /* 262144 ints */
#define OFF_VALID 917504     /* 8192 ints */
#define OFF_P1    925696     /* 2048 = 32 slots * 2*C1 */
#define OFF_P2    927744     /* 2048 */
#define OFF_P3    929792     /* 4096 = 32 slots * 2*C3 */
#define OFF_PAR1  933888     /* 64 */
#define OFF_PAR2  933952     /* 64 */
#define OFF_PAR3  934016     /* 128 */

/* ---- pack pc+feat into AoS g[B][N][20] for fast gathers; zero stat partials ---- */
__global__ __launch_bounds__(256) void k_pack(const float* __restrict__ pc,
                                              const float* __restrict__ feat,
                                              float* __restrict__ g,
                                              float* __restrict__ partials) {
  const int t = blockIdx.x * 256 + threadIdx.x;        /* 0..32767 */
  if (t < 8192) partials[t] = 0.f;                      /* zeros P1,P2,P3 (contiguous) */
  const int b = t >> 13;
  const int j = t & (NP - 1);
  const float* pcb = pc + b * 3 * NP;
  float* gp = g + (size_t)t * 20;
  gp[0] = pcb[j];
  gp[1] = pcb[NP + j];
  gp[2] = pcb[2 * NP + j];
  const float* fb = feat + b * 16 * NP;
#pragma unroll
  for (int c = 0; c < 16; c++) gp[3 + c] = fb[c * NP + j];
  gp[19] = 0.f;
}

/* ---- ball query: one wave per query, 4 points/lane, early exit at K found ---- */
__global__ __launch_bounds__(256) void k_ballquery(const float* __restrict__ pc,
                                                   const float* __restrict__ newpc,
                                                   int* __restrict__ idx,
                                                   int* __restrict__ valid) {
  __shared__ int buf[4][KK];
  const int tid = threadIdx.x;
  const int w = tid >> 6, lane = tid & 63;
  const int gq = blockIdx.x * 4 + w;                    /* 0..8191 */
  const int b = gq >> 11, s = gq & (NS - 1);
  const float* np0 = newpc + b * 3 * NS;
  const float qx = np0[s], qy = np0[NS + s], qz = np0[2 * NS + s];
  const float* px = pc + b * 3 * NP;
  const float* py = px + NP;
  const float* pz = px + 2 * NP;
  if (lane == 0) buf[w][0] = 0;
  int cnt = 0;
  for (int j0 = 0; j0 < NP; j0 += 256) {
    const int jb = j0 + lane * 4;
    const float4 vx = *(const float4*)(px + jb);
    const float4 vy = *(const float4*)(py + jb);
    const float4 vz = *(const float4*)(pz + jb);
    int mm = 0;
    /* d2 with separate rounding, ((dx*dx + dy*dy) + dz*dz), to bit-match np f32 */
    {
      float dx = __fsub_rn(qx, vx.x), dy = __fsub_rn(qy, vy.x), dz = __fsub_rn(qz, vz.x);
      if (__fadd_rn(__fadd_rn(__fmul_rn(dx, dx), __fmul_rn(dy, dy)), __fmul_rn(dz, dz)) < BQ_RADIUS2) mm |= 1;
    }
    {
      float dx = __fsub_rn(qx, vx.y), dy = __fsub_rn(qy, vy.y), dz = __fsub_rn(qz, vz.y);
      if (__fadd_rn(__fadd_rn(__fmul_rn(dx, dx), __fmul_rn(dy, dy)), __fmul_rn(dz, dz)) < BQ_RADIUS2) mm |= 2;
    }
    {
      float dx = __fsub_rn(qx, vx.z), dy = __fsub_rn(qy, vy.z), dz = __fsub_rn(qz, vz.z);
      if (__fadd_rn(__fadd_rn(__fmul_rn(dx, dx), __fmul_rn(dy, dy)), __fmul_rn(dz, dz)) < BQ_RADIUS2) mm |= 4;
    }
    {
      float dx = __fsub_rn(qx, vx.w), dy = __fsub_rn(qy, vy.w), dz = __fsub_rn(qz, vz.w);
      if (__fadd_rn(__fadd_rn(__fmul_rn(dx, dx), __fmul_rn(dy, dy)), __fmul_rn(dz, dz)) < BQ_RADIUS2) mm |= 8;
    }
    const int c4 = __popc(mm);
    int pre = c4;                                       /* inclusive wave prefix-sum */
#pragma unroll
    for (int off = 1; off < 64; off <<= 1) {
      int v = __shfl_up(pre, off);
      if (lane >= off) pre += v;
    }
    const int total = __shfl(pre, 63);
    if (mm) {
      int base = cnt + pre - c4;
#pragma unroll
      for (int i = 0; i < 4; i++) {
        if ((mm >> i) & 1) {
          if (base < KK) buf[w][base] = jb + i;
          base++;
        }
      }
    }
    cnt += total;
    if (cnt >= KK) break;
  }
  __syncthreads();
  if (lane < KK) {
    const int f = cnt < KK ? cnt : KK;
    const int i0 = buf[w][0];                           /* 0 if cnt==0 */
    idx[gq * KK + lane] = (lane < f) ? buf[w][lane] : i0;
  }
  if (lane == 0) valid[gq] = (cnt > 0);
}

/* ---- gather + conv1 (19->32) + stats1; writes channels 0..31 of out.
   Stats folded into the output loop (no per-thread arrays -> no scratch):
   16-lane row butterfly (masks 1,2,4,8) then row-leader LDS write. ---- */
__global__ __launch_bounds__(256) void k_conv1(const float* __restrict__ g,
                                               const int* __restrict__ idx,
                                               const float* __restrict__ newpc,
                                               const float* __restrict__ w1,
                                               const float* __restrict__ b1,
                                               float* __restrict__ y,
                                               float* __restrict__ partial) {
  __shared__ float wl[C1 * 20];
  __shared__ float bl[C1];
  __shared__ float red[16][2 * C1 + 1];
  const int tid = threadIdx.x;
  for (int i = tid; i < C1 * 20; i += 256) {
    const int o = i / 20, c = i - o * 20;
    wl[i] = (c < 19) ? w1[o * 19 + c] : 0.f;
  }
  if (tid < C1) bl[tid] = b1[tid];
  __syncthreads();
  const int pos = blockIdx.x * 256 + tid;
  const int b = pos >> 16;
  const int r = pos & (RTOT - 1);
  const int s = r >> 5;
  const int j = idx[pos];
  const float4* gp = (const float4*)(g + (size_t)(b * NP + j) * 20);
  const float4 v0 = gp[0], v1 = gp[1], v2 = gp[2], v3 = gp[3], v4 = gp[4];
  const float* np0 = newpc + b * 3 * NS;
  float xr[20];
  xr[0] = v0.x - np0[s]; xr[1] = v0.y - np0[NS + s]; xr[2] = v0.z - np0[2 * NS + s]; xr[3] = v0.w;
  xr[4] = v1.x; xr[5] = v1.y; xr[6] = v1.z; xr[7] = v1.w;
  xr[8] = v2.x; xr[9] = v2.y; xr[10] = v2.z; xr[11] = v2.w;
  xr[12] = v3.x; xr[13] = v3.y; xr[14] = v3.z; xr[15] = v3.w;
  xr[16] = v4.x; xr[17] = v4.y; xr[18] = v4.z; xr[19] = v4.w;   /* pad = 0 */
  float* yb = y + ((size_t)b * C3) * RTOT + r;          /* batch stride = 64 channels */
  const int grp = tid >> 4;
  const bool lead = (tid & 15) == 0;
#pragma unroll
  for (int o = 0; o < C1; o++) {
    float acc = bl[o];
    const float4* wr = (const float4*)&wl[o * 20];
#pragma unroll
    for (int ct = 0; ct < 5; ct++) {
      const float4 wv = wr[ct];
      acc = fmaf(wv.x, xr[4 * ct + 0], acc);
      acc = fmaf(wv.y, xr[4 * ct + 1], acc);
      acc = fmaf(wv.z, xr[4 * ct + 2], acc);
      acc = fmaf(wv.w, xr[4 * ct + 3], acc);
    }
    yb[(size_t)o * RTOT] = acc;
    float a = acc, q = acc * acc;
    a += __shfl_xor(a, 1); q += __shfl_xor(q, 1);
    a += __shfl_xor(a, 2); q += __shfl_xor(q, 2);
    a += __shfl_xor(a, 4); q += __shfl_xor(q, 4);
    a += __shfl_xor(a, 8); q += __shfl_xor(q, 8);
    if (lead) { red[grp][o] = a; red[grp][C1 + o] = q; }
  }
  __syncthreads();
  if (tid < 2 * C1) {
    float v = 0.f;
#pragma unroll
    for (int gq = 0; gq < 16; gq++) v += red[gq][tid];
    atomicAdd(&partial[(blockIdx.x & (NSLOT - 1)) * 2 * C1 + tid], v);
  }
}

/* ---- bn1+relu fused load, conv2 (32->32) in-place on channels 0..31, stats2 ---- */
__global__ __launch_bounds__(256) void k_conv2(const float* __restrict__ w2,
                                               const float* __restrict__ b2,
                                               const float* __restrict__ par,
                                               float* y,
                                               float* __restrict__ partial) {
  __shared__ float wl[C2 * C1];
  __shared__ float bl[C2];
  __shared__ float pl[2 * C1];
  __shared__ float red[16][2 * C2 + 1];
  const int tid = threadIdx.x;
  for (int i = tid; i < C2 * C1; i += 256) wl[i] = w2[i];
  if (tid < C2) bl[tid] = b2[tid];
  if (tid < 2 * C1) pl[tid] = par[tid];
  __syncthreads();
  const int pos = blockIdx.x * 256 + tid;
  const int b = pos >> 16;
  const int r = pos & (RTOT - 1);
  float* yb = y + ((size_t)b * C3) * RTOT + r;
  float xr[C1];
#pragma unroll
  for (int c = 0; c < C1; c++) {
    const float v = yb[(size_t)c * RTOT];
    xr[c] = fmaxf(fmaf(v, pl[c], pl[C1 + c]), 0.f);
  }
  const int grp = tid >> 4;
  const bool lead = (tid & 15) == 0;
#pragma unroll
  for (int o = 0; o < C2; o++) {
    float acc = bl[o];
    const float4* wr = (const float4*)&wl[o * C1];
#pragma unroll
    for (int ct = 0; ct < C1 / 4; ct++) {
      const float4 wv = wr[ct];
      acc = fmaf(wv.x, xr[4 * ct + 0], acc);
      acc = fmaf(wv.y, xr[4 * ct + 1], acc);
      acc = fmaf(wv.z, xr[4 * ct + 2], acc);
      acc = fmaf(wv.w, xr[4 * ct + 3], acc);
    }
    yb[(size_t)o * RTOT] = acc;
    float a = acc, q = acc * acc;
    a += __shfl_xor(a, 1); q += __shfl_xor(q, 1);
    a += __shfl_xor(a, 2); q += __shfl_xor(q, 2);
    a += __shfl_xor(a, 4); q += __shfl_xor(q, 4);
    a += __shfl_xor(a, 8); q += __shfl_xor(q, 8);
    if (lead) { red[grp][o] = a; red[grp][C2 + o] = q; }
  }
  __syncthreads();
  if (tid < 2 * C2) {
    float v = 0.f;
#pragma unroll
    for (int gq = 0; gq < 16; gq++) v += red[gq][tid];
    atomicAdd(&partial[(blockIdx.x & (NSLOT - 1)) * 2 * C2 + tid], v);
  }
}

/* ---- bn2+relu fused load, conv3 (32->64) in-place -> all 64 channels, stats3.
   One thread owns its whole (b,r) column: reads ch 0..31 to regs, then
   overwrites ch 0..63 of the same column — race-free in-place. ---- */
__global__ __launch_bounds__(256) void k_conv3(const float* __restrict__ w3,
                                               const float* __restrict__ b3,
                                               const float* __restrict__ par,
                                               float* y,
                                               float* __restrict__ partial) {
  __shared__ float wl[C3 * C2];
  __shared__ float bl[C3];
  __shared__ float pl[2 * C2];
  __shared__ float red[16][2 * C3 + 1];
  const int tid = threadIdx.x;
  for (int i = tid; i < C3 * C2; i += 256) wl[i] = w3[i];
  if (tid < C3) bl[tid] = b3[tid];
  if (tid < 2 * C2) pl[tid] = par[tid];
  __syncthreads();
  const int pos = blockIdx.x * 256 + tid;
  const int b = pos >> 16;
  const int r = pos & (RTOT - 1);
  float* yb = y + ((size_t)b * C3) * RTOT + r;
  float xr[C2];
#pragma unroll
  for (int c = 0; c < C2; c++) {
    const float v = yb[(size_t)c * RTOT];
    xr[c] = fmaxf(fmaf(v, pl[c], pl[C2 + c]), 0.f);
  }
  const int grp = tid >> 4;
  const bool lead = (tid & 15) == 0;
#pragma unroll
  for (int o = 0; o < C3; o++) {
    float acc = bl[o];
    const float4* wr = (const float4*)&wl[o * C2];
#pragma unroll
    for (int ct = 0; ct < C2 / 4; ct++) {
      const float4 wv = wr[ct];
      acc = fmaf(wv.x, xr[4 * ct + 0], acc);
      acc = fmaf(wv.y, xr[4 * ct + 1], acc);
      acc = fmaf(wv.z, xr[4 * ct + 2], acc);
      acc = fmaf(wv.w, xr[4 * ct + 3], acc);
    }
    yb[(size_t)o * RTOT] = acc;
    float a = acc, q = acc * acc;
    a += __shfl_xor(a, 1); q += __shfl_xor(q, 1);
    a += __shfl_xor(a, 2); q += __shfl_xor(q, 2);
    a += __shfl_xor(a, 4); q += __shfl_xor(q, 4);
    a += __shfl_xor(a, 8); q += __shfl_xor(q, 8);
    if (lead) { red[grp][o] = a; red[grp][C3 + o] = q; }
  }
  __syncthreads();
  if (tid < 2 * C3) {
    float v = 0.f;
#pragma unroll
    for (int gq = 0; gq < 16; gq++) v += red[gq][tid];
    atomicAdd(&partial[(blockIdx.x & (NSLOT - 1)) * 2 * C3 + tid], v);
  }
}

/* ---- finalize BN params for one layer: partial sums -> (scale, shift) ---- */
__global__ void k_params(const float* __restrict__ partial,
                         const float* __restrict__ gamma,
                         const float* __restrict__ beta,
                         float* __restrict__ params, int C) {
  __shared__ float tot[2 * C3];
  const int t = threadIdx.x;                 /* blockDim == 2C */
  float v = 0.f;
#pragma unroll 1
  for (int sl = 0; sl < NSLOT; ++sl) v += partial[sl * 2 * C + t];
  tot[t] = v;
  __syncthreads();
  if (t < C) {
    const float inv = 1.0f / (float)MTOT;
    const float mean = tot[t] * inv;
    const float ex2 = tot[C + t] * inv;
    const float var = ex2 - mean * mean;
    const float sc = gamma[t] * rsqrtf(var + EPSBN);
    params[t] = sc;
    params[C + t] = beta[t] - mean * sc;
  }
}

/* ---- bn3 + relu + validity mask, in-place on d_out ---- */
__global__ __launch_bounds__(256) void k_final(float* __restrict__ out,
                                               const float* __restrict__ par,
                                               const int* __restrict__ valid) {
  const int t = blockIdx.x * 256 + threadIdx.x;   /* 0..4194303 (float4 per thread) */
  const size_t e = (size_t)t * 4;
  const int b = t >> 20;
  const int o = (t >> 14) & 63;
  const int s = (t & 16383) >> 3;
  const float sc = par[o], sh = par[C3 + o];
  const float m = valid[(b << 11) + s] ? 1.f : 0.f;
  float4 v = *(float4*)(out + e);
  v.x = fmaxf(fmaf(v.x, sc, sh), 0.f) * m;
  v.y = fmaxf(fmaf(v.y, sc, sh), 0.f) * m;
  v.z = fmaxf(fmaf(v.z, sc, sh), 0.f) * m;
  v.w = fmaxf(fmaf(v.w, sc, sh), 0.f) * m;
  *(float4*)(out + e) = v;
}

extern "C" void kernel_launch(void* const* d_in, const int* in_sizes, int n_in,
                              void* d_out, int out_size, void* d_ws, size_t ws_size,
                              hipStream_t stream) {
  const float* pc    = (const float*)d_in[0];
  const float* feat  = (const float*)d_in[1];
  const float* newpc = (const float*)d_in[2];
  const float* w1 = (const float*)d_in[3];
  const float* b1 = (const float*)d_in[4];
  const float* g1 = (const float*)d_in[5];
  const float* be1 = (const float*)d_in[6];
  const float* w2 = (const float*)d_in[7];
  const float* b2 = (const float*)d_in[8];
  const float* g2 = (const float*)d_in[9];
  const float* be2 = (const float*)d_in[10];
  const float* w3 = (const float*)d_in[11];
  const float* b3 = (const float*)d_in[12];
  const float* g3 = (const float*)d_in[13];
  const float* be3 = (const float*)d_in[14];

  float* ws = (float*)d_ws;
  float* gbuf  = ws + OFF_G;
  int*   idx   = (int*)(ws + OFF_IDX);
  int*   valid = (int*)(ws + OFF_VALID);
  float* p1 = ws + OFF_P1;
  float* p2 = ws + OFF_P2;
  float* p3 = ws + OFF_P3;
  float* par1 = ws + OFF_PAR1;
  float* par2 = ws + OFF_PAR2;
  float* par3 = ws + OFF_PAR3;
  float* out = (float*)d_out;

  k_pack<<<dim3(128), dim3(256), 0, stream>>>(pc, feat, gbuf, p1);
  k_ballquery<<<dim3(2048), dim3(256), 0, stream>>>(pc, newpc, idx, valid);
  k_conv1<<<dim3(1024), dim3(256), 0, stream>>>(gbuf, idx, newpc, w1, b1, out, p1);
  k_params<<<dim3(1), dim3(2 * C1), 0, stream>>>(p1, g1, be1, par1, C1);
  k_conv2<<<dim3(1024), dim3(256), 0, stream>>>(w2, b2, par1, out, p2);
  k_params<<<dim3(1), dim3(2 * C2), 0, stream>>>(p2, g2, be2, par2, C2);
  k_conv3<<<dim3(1024), dim3(256), 0, stream>>>(w3, b3, par2, out, p3);
  k_params<<<dim3(1), dim3(2 * C3), 0, stream>>>(p3, g3, be3, par3, C3);
  k_final<<<dim3(16384), dim3(256), 0, stream>>>(out, par3, valid);
}

// Round 4
// 245.457 us; speedup vs baseline: 1.2421x; 1.1305x over previous
//
#include <hip/hip_runtime.h>

#define BQ_RADIUS2 0.25f
#define KK 32
#define NB 4
#define NP 8192
#define NS 2048
#define C1 32
#define C2 32
#define C3 64
#define EPSBN 1e-5f
#define RTOT 65536          /* S*K */
#define MTOT (NB*NS*KK)     /* 262144 */
#define NSLOT 32

/* workspace offsets (in 4-byte elements) — total 934144 floats = 3.74 MB.
   Intermediate activations live INSIDE d_out (channels 0..31 of [B][64][RTOT]). */
#define OFF_G     0          /* 655360: packed [B][N][20] = xyz + 16 feat + pad */
#define OFF_IDX   655360     /* 262144 ints */
#define OFF_VALID 917504     /* 8192 ints */
#define OFF_P1    925696     /* 2048 = 32 slots * 2*C1 */
#define OFF_P2    927744     /* 2048 */
#define OFF_P3    929792     /* 4096 */
#define OFF_PAR1  933888     /* 64 */
#define OFF_PAR2  933952     /* 64 */
#define OFF_PAR3  934016     /* 128 */

/* ---- pack pc+feat into AoS g[B][N][20]; zero stat partials ---- */
__global__ __launch_bounds__(256) void k_pack(const float* __restrict__ pc,
                                              const float* __restrict__ feat,
                                              float* __restrict__ g,
                                              float* __restrict__ partials) {
  const int t = blockIdx.x * 256 + threadIdx.x;        /* 0..32767 */
  if (t < 8192) partials[t] = 0.f;                      /* zeros P1,P2,P3 (contiguous) */
  const int b = t >> 13;
  const int j = t & (NP - 1);
  const float* pcb = pc + b * 3 * NP;
  float* gp = g + (size_t)t * 20;
  gp[0] = pcb[j];
  gp[1] = pcb[NP + j];
  gp[2] = pcb[2 * NP + j];
  const float* fb = feat + b * 16 * NP;
#pragma unroll
  for (int c = 0; c < 16; c++) gp[3 + c] = fb[c * NP + j];
  gp[19] = 0.f;
}

/* ---- ball query: one wave per query, 4 points/lane, early exit at K found ---- */
__global__ __launch_bounds__(256) void k_ballquery(const float* __restrict__ pc,
                                                   const float* __restrict__ newpc,
                                                   int* __restrict__ idx,
                                                   int* __restrict__ valid) {
  __shared__ int buf[4][KK];
  const int tid = threadIdx.x;
  const int w = tid >> 6, lane = tid & 63;
  const int gq = blockIdx.x * 4 + w;                    /* 0..8191 */
  const int b = gq >> 11, s = gq & (NS - 1);
  const float* np0 = newpc + b * 3 * NS;
  const float qx = np0[s], qy = np0[NS + s], qz = np0[2 * NS + s];
  const float* px = pc + b * 3 * NP;
  const float* py = px + NP;
  const float* pz = px + 2 * NP;
  if (lane == 0) buf[w][0] = 0;
  int cnt = 0;
  for (int j0 = 0; j0 < NP; j0 += 256) {
    const int jb = j0 + lane * 4;
    const float4 vx = *(const float4*)(px + jb);
    const float4 vy = *(const float4*)(py + jb);
    const float4 vz = *(const float4*)(pz + jb);
    int mm = 0;
    /* d2 with separate rounding, ((dx*dx + dy*dy) + dz*dz), to bit-match np f32 */
    {
      float dx = __fsub_rn(qx, vx.x), dy = __fsub_rn(qy, vy.x), dz = __fsub_rn(qz, vz.x);
      if (__fadd_rn(__fadd_rn(__fmul_rn(dx, dx), __fmul_rn(dy, dy)), __fmul_rn(dz, dz)) < BQ_RADIUS2) mm |= 1;
    }
    {
      float dx = __fsub_rn(qx, vx.y), dy = __fsub_rn(qy, vy.y), dz = __fsub_rn(qz, vz.y);
      if (__fadd_rn(__fadd_rn(__fmul_rn(dx, dx), __fmul_rn(dy, dy)), __fmul_rn(dz, dz)) < BQ_RADIUS2) mm |= 2;
    }
    {
      float dx = __fsub_rn(qx, vx.z), dy = __fsub_rn(qy, vy.z), dz = __fsub_rn(qz, vz.z);
      if (__fadd_rn(__fadd_rn(__fmul_rn(dx, dx), __fmul_rn(dy, dy)), __fmul_rn(dz, dz)) < BQ_RADIUS2) mm |= 4;
    }
    {
      float dx = __fsub_rn(qx, vx.w), dy = __fsub_rn(qy, vy.w), dz = __fsub_rn(qz, vz.w);
      if (__fadd_rn(__fadd_rn(__fmul_rn(dx, dx), __fmul_rn(dy, dy)), __fmul_rn(dz, dz)) < BQ_RADIUS2) mm |= 8;
    }
    const int c4 = __popc(mm);
    int pre = c4;                                       /* inclusive wave prefix-sum */
#pragma unroll
    for (int off = 1; off < 64; off <<= 1) {
      int v = __shfl_up(pre, off);
      if (lane >= off) pre += v;
    }
    const int total = __shfl(pre, 63);
    if (mm) {
      int base = cnt + pre - c4;
#pragma unroll
      for (int i = 0; i < 4; i++) {
        if ((mm >> i) & 1) {
          if (base < KK) buf[w][base] = jb + i;
          base++;
        }
      }
    }
    cnt += total;
    if (cnt >= KK) break;
  }
  __syncthreads();
  if (lane < KK) {
    const int f = cnt < KK ? cnt : KK;
    const int i0 = buf[w][0];                           /* 0 if cnt==0 */
    idx[gq * KK + lane] = (lane < f) ? buf[w][lane] : i0;
  }
  if (lane == 0) valid[gq] = (cnt > 0);
}

/* ---- gather + conv1 (19->32), V=4 positions/thread, stats1 ---- */
__global__ __launch_bounds__(256, 1) void k_conv1(const float* __restrict__ g,
                                                  const int* __restrict__ idx,
                                                  const float* __restrict__ newpc,
                                                  const float* __restrict__ w1,
                                                  const float* __restrict__ b1,
                                                  float* __restrict__ y,
                                                  float* __restrict__ partial) {
  __shared__ float wl[C1 * 20];
  __shared__ float bl[C1];
  __shared__ float red[16][2 * C1 + 1];
  const int tid = threadIdx.x;
  for (int i = tid; i < C1 * 20; i += 256) {
    const int o = i / 20, c = i - o * 20;
    wl[i] = (c < 19) ? w1[o * 19 + c] : 0.f;
  }
  if (tid < C1) bl[tid] = b1[tid];
  __syncthreads();
  const int pos = blockIdx.x * 256 + tid;               /* 0..65535 */
  const int p4 = pos << 2;
  const int b = p4 >> 16;
  const int r = p4 & (RTOT - 1);
  const int s = r >> 5;                                 /* r..r+3 share s */
  const int4 jj = *(const int4*)(idx + p4);
  const float* np0 = newpc + b * 3 * NS;
  const float nx = np0[s], ny = np0[NS + s], nz = np0[2 * NS + s];
  float4 xr[20];
#define LOADPT(COMP, J) { \
    const float4* gp = (const float4*)(g + (size_t)(b * NP + (J)) * 20); \
    const float4 a0 = gp[0], a1 = gp[1], a2 = gp[2], a3 = gp[3], a4 = gp[4]; \
    xr[0].COMP = a0.x - nx; xr[1].COMP = a0.y - ny; xr[2].COMP = a0.z - nz; xr[3].COMP = a0.w; \
    xr[4].COMP = a1.x; xr[5].COMP = a1.y; xr[6].COMP = a1.z; xr[7].COMP = a1.w; \
    xr[8].COMP = a2.x; xr[9].COMP = a2.y; xr[10].COMP = a2.z; xr[11].COMP = a2.w; \
    xr[12].COMP = a3.x; xr[13].COMP = a3.y; xr[14].COMP = a3.z; xr[15].COMP = a3.w; \
    xr[16].COMP = a4.x; xr[17].COMP = a4.y; xr[18].COMP = a4.z; xr[19].COMP = a4.w; }
  LOADPT(x, jj.x) LOADPT(y, jj.y) LOADPT(z, jj.z) LOADPT(w, jj.w)
#undef LOADPT
  float* yb = y + ((size_t)b * C3) * RTOT + r;
  const int grp = tid >> 4;
  const bool lead = (tid & 15) == 0;
#pragma unroll 4
  for (int o = 0; o < C1; o++) {
    const float bo = bl[o];
    float4 acc = make_float4(bo, bo, bo, bo);
    const float4* wr = (const float4*)&wl[o * 20];
#pragma unroll
    for (int ct = 0; ct < 5; ct++) {
      const float4 wv = wr[ct];
      const float4 x0 = xr[4 * ct + 0], x1 = xr[4 * ct + 1], x2 = xr[4 * ct + 2], x3 = xr[4 * ct + 3];
      acc.x = fmaf(wv.x, x0.x, acc.x); acc.y = fmaf(wv.x, x0.y, acc.y);
      acc.z = fmaf(wv.x, x0.z, acc.z); acc.w = fmaf(wv.x, x0.w, acc.w);
      acc.x = fmaf(wv.y, x1.x, acc.x); acc.y = fmaf(wv.y, x1.y, acc.y);
      acc.z = fmaf(wv.y, x1.z, acc.z); acc.w = fmaf(wv.y, x1.w, acc.w);
      acc.x = fmaf(wv.z, x2.x, acc.x); acc.y = fmaf(wv.z, x2.y, acc.y);
      acc.z = fmaf(wv.z, x2.z, acc.z); acc.w = fmaf(wv.z, x2.w, acc.w);
      acc.x = fmaf(wv.w, x3.x, acc.x); acc.y = fmaf(wv.w, x3.y, acc.y);
      acc.z = fmaf(wv.w, x3.z, acc.z); acc.w = fmaf(wv.w, x3.w, acc.w);
    }
    *(float4*)(yb + (size_t)o * RTOT) = acc;
    float a = (acc.x + acc.y) + (acc.z + acc.w);
    float q = (acc.x * acc.x + acc.y * acc.y) + (acc.z * acc.z + acc.w * acc.w);
    a += __shfl_xor(a, 1); q += __shfl_xor(q, 1);
    a += __shfl_xor(a, 2); q += __shfl_xor(q, 2);
    a += __shfl_xor(a, 4); q += __shfl_xor(q, 4);
    a += __shfl_xor(a, 8); q += __shfl_xor(q, 8);
    if (lead) { red[grp][o] = a; red[grp][C1 + o] = q; }
  }
  __syncthreads();
  if (tid < 2 * C1) {
    float v = 0.f;
#pragma unroll
    for (int gq = 0; gq < 16; gq++) v += red[gq][tid];
    atomicAdd(&partial[(blockIdx.x & (NSLOT - 1)) * 2 * C1 + tid], v);
  }
}

/* ---- bn1+relu load, conv2 (32->32) in-place, V=4, stats2 ---- */
__global__ __launch_bounds__(256, 1) void k_conv2(const float* __restrict__ w2,
                                                  const float* __restrict__ b2,
                                                  const float* __restrict__ par,
                                                  float* y,
                                                  float* __restrict__ partial) {
  __shared__ float wl[C2 * C1];
  __shared__ float bl[C2];
  __shared__ float pl[2 * C1];
  __shared__ float red[16][2 * C2 + 1];
  const int tid = threadIdx.x;
  for (int i = tid; i < C2 * C1; i += 256) wl[i] = w2[i];
  if (tid < C2) bl[tid] = b2[tid];
  if (tid < 2 * C1) pl[tid] = par[tid];
  __syncthreads();
  const int pos = blockIdx.x * 256 + tid;
  const int p4 = pos << 2;
  const int b = p4 >> 16;
  const int r = p4 & (RTOT - 1);
  float* yb = y + ((size_t)b * C3) * RTOT + r;
  float4 xr[C1];
#pragma unroll
  for (int c = 0; c < C1; c++) {
    float4 v = *(const float4*)(yb + (size_t)c * RTOT);
    const float sc = pl[c], sh = pl[C1 + c];
    v.x = fmaxf(fmaf(v.x, sc, sh), 0.f);
    v.y = fmaxf(fmaf(v.y, sc, sh), 0.f);
    v.z = fmaxf(fmaf(v.z, sc, sh), 0.f);
    v.w = fmaxf(fmaf(v.w, sc, sh), 0.f);
    xr[c] = v;
  }
  const int grp = tid >> 4;
  const bool lead = (tid & 15) == 0;
#pragma unroll 4
  for (int o = 0; o < C2; o++) {
    const float bo = bl[o];
    float4 acc = make_float4(bo, bo, bo, bo);
    const float4* wr = (const float4*)&wl[o * C1];
#pragma unroll
    for (int ct = 0; ct < C1 / 4; ct++) {
      const float4 wv = wr[ct];
      const float4 x0 = xr[4 * ct + 0], x1 = xr[4 * ct + 1], x2 = xr[4 * ct + 2], x3 = xr[4 * ct + 3];
      acc.x = fmaf(wv.x, x0.x, acc.x); acc.y = fmaf(wv.x, x0.y, acc.y);
      acc.z = fmaf(wv.x, x0.z, acc.z); acc.w = fmaf(wv.x, x0.w, acc.w);
      acc.x = fmaf(wv.y, x1.x, acc.x); acc.y = fmaf(wv.y, x1.y, acc.y);
      acc.z = fmaf(wv.y, x1.z, acc.z); acc.w = fmaf(wv.y, x1.w, acc.w);
      acc.x = fmaf(wv.z, x2.x, acc.x); acc.y = fmaf(wv.z, x2.y, acc.y);
      acc.z = fmaf(wv.z, x2.z, acc.z); acc.w = fmaf(wv.z, x2.w, acc.w);
      acc.x = fmaf(wv.w, x3.x, acc.x); acc.y = fmaf(wv.w, x3.y, acc.y);
      acc.z = fmaf(wv.w, x3.z, acc.z); acc.w = fmaf(wv.w, x3.w, acc.w);
    }
    *(float4*)(yb + (size_t)o * RTOT) = acc;
    float a = (acc.x + acc.y) + (acc.z + acc.w);
    float q = (acc.x * acc.x + acc.y * acc.y) + (acc.z * acc.z + acc.w * acc.w);
    a += __shfl_xor(a, 1); q += __shfl_xor(q, 1);
    a += __shfl_xor(a, 2); q += __shfl_xor(q, 2);
    a += __shfl_xor(a, 4); q += __shfl_xor(q, 4);
    a += __shfl_xor(a, 8); q += __shfl_xor(q, 8);
    if (lead) { red[grp][o] = a; red[grp][C2 + o] = q; }
  }
  __syncthreads();
  if (tid < 2 * C2) {
    float v = 0.f;
#pragma unroll
    for (int gq = 0; gq < 16; gq++) v += red[gq][tid];
    atomicAdd(&partial[(blockIdx.x & (NSLOT - 1)) * 2 * C2 + tid], v);
  }
}

/* ---- bn2+relu load, conv3 (32->64) in-place, V=4, stats3.
   Thread owns all 64 channels of its 4 columns -> race-free in-place. ---- */
__global__ __launch_bounds__(256, 1) void k_conv3(const float* __restrict__ w3,
                                                  const float* __restrict__ b3,
                                                  const float* __restrict__ par,
                                                  float* y,
                                                  float* __restrict__ partial) {
  __shared__ float wl[C3 * C2];
  __shared__ float bl[C3];
  __shared__ float pl[2 * C2];
  __shared__ float red[16][2 * C3 + 1];
  const int tid = threadIdx.x;
  for (int i = tid; i < C3 * C2; i += 256) wl[i] = w3[i];
  if (tid < C3) bl[tid] = b3[tid];
  if (tid < 2 * C2) pl[tid] = par[tid];
  __syncthreads();
  const int pos = blockIdx.x * 256 + tid;
  const int p4 = pos << 2;
  const int b = p4 >> 16;
  const int r = p4 & (RTOT - 1);
  float* yb = y + ((size_t)b * C3) * RTOT + r;
  float4 xr[C2];
#pragma unroll
  for (int c = 0; c < C2; c++) {
    float4 v = *(const float4*)(yb + (size_t)c * RTOT);
    const float sc = pl[c], sh = pl[C2 + c];
    v.x = fmaxf(fmaf(v.x, sc, sh), 0.f);
    v.y = fmaxf(fmaf(v.y, sc, sh), 0.f);
    v.z = fmaxf(fmaf(v.z, sc, sh), 0.f);
    v.w = fmaxf(fmaf(v.w, sc, sh), 0.f);
    xr[c] = v;
  }
  const int grp = tid >> 4;
  const bool lead = (tid & 15) == 0;
#pragma unroll 4
  for (int o = 0; o < C3; o++) {
    const float bo = bl[o];
    float4 acc = make_float4(bo, bo, bo, bo);
    const float4* wr = (const float4*)&wl[o * C2];
#pragma unroll
    for (int ct = 0; ct < C2 / 4; ct++) {
      const float4 wv = wr[ct];
      const float4 x0 = xr[4 * ct + 0], x1 = xr[4 * ct + 1], x2 = xr[4 * ct + 2], x3 = xr[4 * ct + 3];
      acc.x = fmaf(wv.x, x0.x, acc.x); acc.y = fmaf(wv.x, x0.y, acc.y);
      acc.z = fmaf(wv.x, x0.z, acc.z); acc.w = fmaf(wv.x, x0.w, acc.w);
      acc.x = fmaf(wv.y, x1.x, acc.x); acc.y = fmaf(wv.y, x1.y, acc.y);
      acc.z = fmaf(wv.y, x1.z, acc.z); acc.w = fmaf(wv.y, x1.w, acc.w);
      acc.x = fmaf(wv.z, x2.x, acc.x); acc.y = fmaf(wv.z, x2.y, acc.y);
      acc.z = fmaf(wv.z, x2.z, acc.z); acc.w = fmaf(wv.z, x2.w, acc.w);
      acc.x = fmaf(wv.w, x3.x, acc.x); acc.y = fmaf(wv.w, x3.y, acc.y);
      acc.z = fmaf(wv.w, x3.z, acc.z); acc.w = fmaf(wv.w, x3.w, acc.w);
    }
    *(float4*)(yb + (size_t)o * RTOT) = acc;
    float a = (acc.x + acc.y) + (acc.z + acc.w);
    float q = (acc.x * acc.x + acc.y * acc.y) + (acc.z * acc.z + acc.w * acc.w);
    a += __shfl_xor(a, 1); q += __shfl_xor(q, 1);
    a += __shfl_xor(a, 2); q += __shfl_xor(q, 2);
    a += __shfl_xor(a, 4); q += __shfl_xor(q, 4);
    a += __shfl_xor(a, 8); q += __shfl_xor(q, 8);
    if (lead) { red[grp][o] = a; red[grp][C3 + o] = q; }
  }
  __syncthreads();
  if (tid < 2 * C3) {
    float v = 0.f;
#pragma unroll
    for (int gq = 0; gq < 16; gq++) v += red[gq][tid];
    atomicAdd(&partial[(blockIdx.x & (NSLOT - 1)) * 2 * C3 + tid], v);
  }
}

/* ---- finalize BN params for one layer: partial sums -> (scale, shift) ---- */
__global__ void k_params(const float* __restrict__ partial,
                         const float* __restrict__ gamma,
                         const float* __restrict__ beta,
                         float* __restrict__ params, int C) {
  __shared__ float tot[2 * C3];
  const int t = threadIdx.x;                 /* blockDim == 2C */
  float v = 0.f;
#pragma unroll 1
  for (int sl = 0; sl < NSLOT; ++sl) v += partial[sl * 2 * C + t];
  tot[t] = v;
  __syncthreads();
  if (t < C) {
    const float inv = 1.0f / (float)MTOT;
    const float mean = tot[t] * inv;
    const float ex2 = tot[C + t] * inv;
    const float var = ex2 - mean * mean;
    const float sc = gamma[t] * rsqrtf(var + EPSBN);
    params[t] = sc;
    params[C + t] = beta[t] - mean * sc;
  }
}

/* ---- bn3 + relu + validity mask, in-place on d_out ---- */
__global__ __launch_bounds__(256) void k_final(float* __restrict__ out,
                                               const float* __restrict__ par,
                                               const int* __restrict__ valid) {
  const int t = blockIdx.x * 256 + threadIdx.x;   /* float4 per thread */
  const size_t e = (size_t)t * 4;
  const int b = t >> 20;
  const int o = (t >> 14) & 63;
  const int s = (t & 16383) >> 3;
  const float sc = par[o], sh = par[C3 + o];
  const float m = valid[(b << 11) + s] ? 1.f : 0.f;
  float4 v = *(float4*)(out + e);
  v.x = fmaxf(fmaf(v.x, sc, sh), 0.f) * m;
  v.y = fmaxf(fmaf(v.y, sc, sh), 0.f) * m;
  v.z = fmaxf(fmaf(v.z, sc, sh), 0.f) * m;
  v.w = fmaxf(fmaf(v.w, sc, sh), 0.f) * m;
  *(float4*)(out + e) = v;
}

extern "C" void kernel_launch(void* const* d_in, const int* in_sizes, int n_in,
                              void* d_out, int out_size, void* d_ws, size_t ws_size,
                              hipStream_t stream) {
  const float* pc    = (const float*)d_in[0];
  const float* feat  = (const float*)d_in[1];
  const float* newpc = (const float*)d_in[2];
  const float* w1 = (const float*)d_in[3];
  const float* b1 = (const float*)d_in[4];
  const float* g1 = (const float*)d_in[5];
  const float* be1 = (const float*)d_in[6];
  const float* w2 = (const float*)d_in[7];
  const float* b2 = (const float*)d_in[8];
  const float* g2 = (const float*)d_in[9];
  const float* be2 = (const float*)d_in[10];
  const float* w3 = (const float*)d_in[11];
  const float* b3 = (const float*)d_in[12];
  const float* g3 = (const float*)d_in[13];
  const float* be3 = (const float*)d_in[14];

  float* ws = (float*)d_ws;
  float* gbuf  = ws + OFF_G;
  int*   idx   = (int*)(ws + OFF_IDX);
  int*   valid = (int*)(ws + OFF_VALID);
  float* p1 = ws + OFF_P1;
  float* p2 = ws + OFF_P2;
  float* p3 = ws + OFF_P3;
  float* par1 = ws + OFF_PAR1;
  float* par2 = ws + OFF_PAR2;
  float* par3 = ws + OFF_PAR3;
  float* out = (float*)d_out;

  k_pack<<<dim3(128), dim3(256), 0, stream>>>(pc, feat, gbuf, p1);
  k_ballquery<<<dim3(2048), dim3(256), 0, stream>>>(pc, newpc, idx, valid);
  k_conv1<<<dim3(256), dim3(256), 0, stream>>>(gbuf, idx, newpc, w1, b1, out, p1);
  k_params<<<dim3(1), dim3(2 * C1), 0, stream>>>(p1, g1, be1, par1, C1);
  k_conv2<<<dim3(256), dim3(256), 0, stream>>>(w2, b2, par1, out, p2);
  k_params<<<dim3(1), dim3(2 * C2), 0, stream>>>(p2, g2, be2, par2, C2);
  k_conv3<<<dim3(256), dim3(256), 0, stream>>>(w3, b3, par2, out, p3);
  k_params<<<dim3(1), dim3(2 * C3), 0, stream>>>(p3, g3, be3, par3, C3);
  k_final<<<dim3(16384), dim3(256), 0, stream>>>(out, par3, valid);
}